// Round 1
// baseline (439.415 us; speedup 1.0000x reference)
//
#include <hip/hip_runtime.h>
#include <hip/hip_bf16.h>

// Problem constants (fixed by the reference)
#define C_INC   32
#define C_OUTC  64
#define KNBR    8
#define BN_EPS  1e-5f

// LDS layout: Bt[n][k] transposed weights, padded +8 bf16 (stride 528 B) so
// the b128 fragment reads are bank-conflict-free (lane bank class (n+q)%8,
// disjoint 4-bank sets).
#define BT_STRIDE 264

typedef __bf16 bf16x8 __attribute__((ext_vector_type(8)));
typedef float  floatx4 __attribute__((ext_vector_type(4)));

__device__ inline unsigned short f2bf_bits(float f) {
    unsigned int u = __builtin_bit_cast(unsigned int, f);
    // round-to-nearest-even bf16
    unsigned int r = (u + 0x7FFFu + ((u >> 16) & 1u)) >> 16;
    return (unsigned short)r;
}
__device__ inline __bf16 f2bf(float f) {
    return __builtin_bit_cast(__bf16, f2bf_bits(f));
}

// ---------------------------------------------------------------------------
// K1: gather + GEMM (bf16 MFMA, fp32 accum) + bias, writes raw conv output,
//     and per-block per-channel sum / sumsq partials (no global atomics).
// Block = 256 threads = 4 waves; each wave does 4 tiles of 16 rows
// (block covers 256 output rows). N_OUT % 16 == 0 so tiles are all-or-nothing.
// ---------------------------------------------------------------------------
__global__ __launch_bounds__(256) void conv_kernel(
    const float* __restrict__ data,     // [N_IN, 32]
    const float* __restrict__ weight,   // [256, 64]
    const float* __restrict__ bias,     // [64]
    const int*   __restrict__ neigh,    // [N_OUT, 8]
    float*       __restrict__ out,      // raw conv out [N_OUT, 64]
    float*       __restrict__ partials, // [gridDim.x, 128]
    int n_out)
{
    __shared__ unsigned short Bt[C_OUTC * BT_STRIDE]; // 33792 B
    __shared__ float red[2 * C_OUTC];                 // 512 B

    const int t    = threadIdx.x;
    const int lane = t & 63;
    const int wave = t >> 6;
    const int m16  = lane & 15;  // A-row within tile / B,D column within ntile
    const int q    = lane >> 4;  // quad 0..3

    if (t < 2 * C_OUTC) red[t] = 0.0f;

    // Stage weights -> LDS transposed bf16: Bt[n][k] = bf16(weight[k][n]).
    // Per iteration a wave reads 64 consecutive floats of one k-row (coalesced).
    {
        const int n = t & 63;
        const int g = t >> 6; // 0..3
        #pragma unroll 8
        for (int kk = 0; kk < 64; ++kk) {
            int k = kk * 4 + g;
            Bt[n * BT_STRIDE + k] = f2bf_bits(weight[k * C_OUTC + n]);
        }
    }
    __syncthreads();

    float biasv[4];
    #pragma unroll
    for (int nt = 0; nt < 4; ++nt) biasv[nt] = bias[nt * 16 + m16];

    float s1[4] = {0.f, 0.f, 0.f, 0.f};
    float s2[4] = {0.f, 0.f, 0.f, 0.f};

    const int rowBase = blockIdx.x * 256;

    for (int pass = 0; pass < 4; ++pass) {
        const int tile0 = rowBase + pass * 64 + wave * 16; // first row of tile
        if (tile0 >= n_out) continue; // n_out % 16 == 0 -> whole-tile validity

        floatx4 acc[4];
        #pragma unroll
        for (int nt = 0; nt < 4; ++nt) acc[nt] = (floatx4){0.f, 0.f, 0.f, 0.f};

        const int arow = tile0 + m16;

        #pragma unroll
        for (int ks = 0; ks < KNBR; ++ks) {
            const int nidx = neigh[(size_t)arow * KNBR + ks];
            float4 f0 = {0.f, 0.f, 0.f, 0.f};
            float4 f1 = {0.f, 0.f, 0.f, 0.f};
            if (nidx >= 0) {
                const float4* p =
                    reinterpret_cast<const float4*>(data + (size_t)nidx * C_INC + q * 8);
                f0 = p[0];
                f1 = p[1];
            }
            bf16x8 a;
            a[0] = f2bf(f0.x); a[1] = f2bf(f0.y); a[2] = f2bf(f0.z); a[3] = f2bf(f0.w);
            a[4] = f2bf(f1.x); a[5] = f2bf(f1.y); a[6] = f2bf(f1.z); a[7] = f2bf(f1.w);

            #pragma unroll
            for (int nt = 0; nt < 4; ++nt) {
                const bf16x8 b = *reinterpret_cast<const bf16x8*>(
                    &Bt[(nt * 16 + m16) * BT_STRIDE + ks * 32 + q * 8]);
                acc[nt] = __builtin_amdgcn_mfma_f32_16x16x32_bf16(a, b, acc[nt], 0, 0, 0);
            }
        }

        // Epilogue: bias, store raw, accumulate channel stats.
        // D layout: row = q*4 + r, col = m16 + nt*16.
        #pragma unroll
        for (int nt = 0; nt < 4; ++nt) {
            const int c = nt * 16 + m16;
            #pragma unroll
            for (int r = 0; r < 4; ++r) {
                const int drow = tile0 + q * 4 + r;
                const float v = acc[nt][r] + biasv[nt];
                out[(size_t)drow * C_OUTC + c] = v;
                s1[nt] += v;
                s2[nt] += v * v;
            }
        }
    }

    // Reduce stats over the 4 quads holding each column (lanes l, l^16, l^32, l^48).
    #pragma unroll
    for (int nt = 0; nt < 4; ++nt) {
        #pragma unroll
        for (int off = 16; off < 64; off <<= 1) {
            s1[nt] += __shfl_xor(s1[nt], off, 64);
            s2[nt] += __shfl_xor(s2[nt], off, 64);
        }
    }
    if (q == 0) {
        #pragma unroll
        for (int nt = 0; nt < 4; ++nt) {
            const int c = nt * 16 + m16;
            atomicAdd(&red[c], s1[nt]);
            atomicAdd(&red[C_OUTC + c], s2[nt]);
        }
    }
    __syncthreads();
    if (t < 2 * C_OUTC) {
        partials[(size_t)blockIdx.x * 128 + t] = red[t];
    }
}

// ---------------------------------------------------------------------------
// K2: fold per-block partials -> per-channel scale a = gamma*rstd and
//     shift b = beta - mean*a.  Single block of 128 threads.
// ---------------------------------------------------------------------------
__global__ __launch_bounds__(128) void stats_kernel(
    const float* __restrict__ partials, int nb,
    const float* __restrict__ gamma, const float* __restrict__ beta,
    float* __restrict__ ab, int n_out)
{
    const int t = threadIdx.x;
    float a0 = 0.f, a1 = 0.f, a2 = 0.f, a3 = 0.f;
    int b = 0;
    for (; b + 4 <= nb; b += 4) {
        a0 += partials[(size_t)(b + 0) * 128 + t];
        a1 += partials[(size_t)(b + 1) * 128 + t];
        a2 += partials[(size_t)(b + 2) * 128 + t];
        a3 += partials[(size_t)(b + 3) * 128 + t];
    }
    for (; b < nb; ++b) a0 += partials[(size_t)b * 128 + t];
    const float tot = (a0 + a1) + (a2 + a3);

    __shared__ float s[128];
    s[t] = tot;
    __syncthreads();

    if (t < C_OUTC) {
        const float invN = 1.0f / (float)n_out;
        const float mean = s[t] * invN;
        const float var  = s[C_OUTC + t] * invN - mean * mean;
        const float rstd = rsqrtf(var + BN_EPS);
        const float a    = gamma[t] * rstd;
        ab[t]          = a;
        ab[C_OUTC + t] = beta[t] - mean * a;
    }
}

// ---------------------------------------------------------------------------
// K3: in-place affine normalize: y = raw*a[c] + b[c], float4 (4 channels/thread).
// ---------------------------------------------------------------------------
__global__ __launch_bounds__(256) void bn_kernel(
    float* __restrict__ out, const float* __restrict__ ab, long n4)
{
    const long i = (long)blockIdx.x * blockDim.x + threadIdx.x;
    if (i >= n4) return;
    const int c4 = (int)(i & 15); // 64 channels / 4 per float4
    float4 v = reinterpret_cast<float4*>(out)[i];
    const float4 a = reinterpret_cast<const float4*>(ab)[c4];
    const float4 bb = reinterpret_cast<const float4*>(ab + C_OUTC)[c4];
    v.x = v.x * a.x + bb.x;
    v.y = v.y * a.y + bb.y;
    v.z = v.z * a.z + bb.z;
    v.w = v.w * a.w + bb.w;
    reinterpret_cast<float4*>(out)[i] = v;
}

// ---------------------------------------------------------------------------
extern "C" void kernel_launch(void* const* d_in, const int* in_sizes, int n_in,
                              void* d_out, int out_size, void* d_ws, size_t ws_size,
                              hipStream_t stream) {
    const float* data   = (const float*)d_in[0];
    const float* weight = (const float*)d_in[1];
    const float* bias   = (const float*)d_in[2];
    const float* gamma  = (const float*)d_in[3];
    const float* beta   = (const float*)d_in[4];
    const int*   neigh  = (const int*)d_in[5];

    const int n_out = in_sizes[5] / KNBR; // 250000
    float* out = (float*)d_out;

    const int nb = (n_out + 255) / 256; // blocks for K1 (977)

    // Workspace layout: partials [nb*128] floats, then ab [128] floats.
    float* partials = (float*)d_ws;
    float* ab = partials + (size_t)nb * 128; // byte offset nb*512 (16B aligned)

    hipLaunchKernelGGL(conv_kernel, dim3(nb), dim3(256), 0, stream,
                       data, weight, bias, neigh, out, partials, n_out);
    hipLaunchKernelGGL(stats_kernel, dim3(1), dim3(128), 0, stream,
                       partials, nb, gamma, beta, ab, n_out);
    const long n4 = (long)n_out * C_OUTC / 4; // 4,000,000
    hipLaunchKernelGGL(bn_kernel, dim3((unsigned)((n4 + 255) / 256)), dim3(256), 0, stream,
                       out, ab, n4);
}

// Round 3
// 380.512 us; speedup vs baseline: 1.1548x; 1.1548x over previous
//
#include <hip/hip_runtime.h>
#include <hip/hip_bf16.h>

// Problem constants (fixed by the reference)
#define C_INC   32
#define C_OUTC  64
#define KNBR    8
#define BN_EPS  1e-5f

// LDS weight tile: Bt[n][k] transposed, padded (264 shorts = 528 B stride
// == 132 dwords == 4 mod 32 banks) -> b128 fragment reads are 2-way at worst
// (free per m136).
#define BT_STRIDE 264
// partials transposed: [128 stat-rows][NB_PAD block-columns]
#define NB_PAD 1024

typedef __bf16 bf16x8 __attribute__((ext_vector_type(8)));
typedef float  floatx4 __attribute__((ext_vector_type(4)));

__device__ inline unsigned short f2bf_bits(float f) {
    unsigned int u = __builtin_bit_cast(unsigned int, f);
    unsigned int r = (u + 0x7FFFu + ((u >> 16) & 1u)) >> 16; // RNE
    return (unsigned short)r;
}
__device__ inline __bf16 f2bf(float f) {
    return __builtin_bit_cast(__bf16, f2bf_bits(f));
}

// ---------------------------------------------------------------------------
// K1: gather + bf16 MFMA conv + bias -> raw out, plus per-block channel
//     sum/sumsq partials written TRANSPOSED (contiguous for K2).
// Block = 256 thr = 4 waves; block covers 256 rows (4 passes x 4 waves x 16).
// n_out % 16 == 0 so tile validity is all-or-nothing.
// ---------------------------------------------------------------------------
__global__ __launch_bounds__(256) void conv_kernel(
    const float* __restrict__ data,      // [N_IN, 32]
    const float* __restrict__ weight,    // [256, 64]
    const float* __restrict__ bias,      // [64]
    const int*   __restrict__ neigh,     // [N_OUT, 8]
    float*       __restrict__ out,       // raw conv out [N_OUT, 64]
    float*       __restrict__ partialsT, // [128, NB_PAD]
    int n_out)
{
    __shared__ unsigned short Bt[C_OUTC * BT_STRIDE]; // 33792 B
    __shared__ float red[2 * C_OUTC];                 // 512 B

    const int t    = threadIdx.x;
    const int lane = t & 63;
    const int wave = t >> 6;
    const int m16  = lane & 15;  // A-row in tile / D column (low 4 bits)
    const int q    = lane >> 4;  // quad 0..3

    if (t < 2 * C_OUTC) red[t] = 0.0f;

    // Stage weights -> LDS transposed bf16 (coalesced global reads).
    {
        const int n = t & 63;
        const int g = t >> 6;
        #pragma unroll 8
        for (int kk = 0; kk < 64; ++kk) {
            int k = kk * 4 + g;
            Bt[n * BT_STRIDE + k] = f2bf_bits(weight[k * C_OUTC + n]);
        }
    }
    __syncthreads();

    float biasv[4];
    #pragma unroll
    for (int nt = 0; nt < 4; ++nt) biasv[nt] = bias[nt * 16 + m16];

    float s1[4] = {0.f, 0.f, 0.f, 0.f};
    float s2[4] = {0.f, 0.f, 0.f, 0.f};

    const int rowBase = blockIdx.x * 256;
    const int4* __restrict__ neigh4 = reinterpret_cast<const int4*>(neigh);

    for (int pass = 0; pass < 4; ++pass) {
        const int tile0 = rowBase + pass * 64 + wave * 16;
        if (tile0 >= n_out) continue;

        floatx4 acc[4];
        #pragma unroll
        for (int nt = 0; nt < 4; ++nt) acc[nt] = (floatx4){0.f, 0.f, 0.f, 0.f};

        const int arow = tile0 + m16;

        // All 8 neighbor indices up front (two 16B loads) so the 16 gather
        // loads below can issue together and overlap their latency.
        const int4 nA = neigh4[(size_t)arow * 2 + 0];
        const int4 nB = neigh4[(size_t)arow * 2 + 1];
        int nidxs[KNBR] = {nA.x, nA.y, nA.z, nA.w, nB.x, nB.y, nB.z, nB.w};

        float4 g0[KNBR], g1[KNBR];
        #pragma unroll
        for (int ks = 0; ks < KNBR; ++ks) {
            g0[ks] = (float4){0.f, 0.f, 0.f, 0.f};
            g1[ks] = (float4){0.f, 0.f, 0.f, 0.f};
            if (nidxs[ks] >= 0) {
                const float4* p = reinterpret_cast<const float4*>(
                    data + (size_t)nidxs[ks] * C_INC + q * 8);
                g0[ks] = p[0];
                g1[ks] = p[1];
            }
        }

        #pragma unroll
        for (int ks = 0; ks < KNBR; ++ks) {
            bf16x8 a;
            a[0] = f2bf(g0[ks].x); a[1] = f2bf(g0[ks].y);
            a[2] = f2bf(g0[ks].z); a[3] = f2bf(g0[ks].w);
            a[4] = f2bf(g1[ks].x); a[5] = f2bf(g1[ks].y);
            a[6] = f2bf(g1[ks].z); a[7] = f2bf(g1[ks].w);

            #pragma unroll
            for (int nt = 0; nt < 4; ++nt) {
                const bf16x8 b = *reinterpret_cast<const bf16x8*>(
                    &Bt[(nt * 16 + m16) * BT_STRIDE + ks * 32 + q * 8]);
                acc[nt] = __builtin_amdgcn_mfma_f32_16x16x32_bf16(a, b, acc[nt], 0, 0, 0);
            }
        }

        // Epilogue: bias, store raw, accumulate channel stats.
        // D layout: row = q*4 + r, col = m16 + nt*16.
        #pragma unroll
        for (int nt = 0; nt < 4; ++nt) {
            const int c = nt * 16 + m16;
            #pragma unroll
            for (int r = 0; r < 4; ++r) {
                const int drow = tile0 + q * 4 + r;
                const float v = acc[nt][r] + biasv[nt];
                out[(size_t)drow * C_OUTC + c] = v;
                s1[nt] += v;
                s2[nt] += v * v;
            }
        }
    }

    // Reduce stats over the 4 quads holding each column.
    #pragma unroll
    for (int nt = 0; nt < 4; ++nt) {
        #pragma unroll
        for (int off = 16; off < 64; off <<= 1) {
            s1[nt] += __shfl_xor(s1[nt], off, 64);
            s2[nt] += __shfl_xor(s2[nt], off, 64);
        }
    }
    if (q == 0) {
        #pragma unroll
        for (int nt = 0; nt < 4; ++nt) {
            const int c = nt * 16 + m16;
            atomicAdd(&red[c], s1[nt]);
            atomicAdd(&red[C_OUTC + c], s2[nt]);
        }
    }
    __syncthreads();
    if (t < 2 * C_OUTC) {
        partialsT[(size_t)t * NB_PAD + blockIdx.x] = red[t];
    }
}

// ---------------------------------------------------------------------------
// K2: 64 blocks; block c reduces channel c's sum (row c) and sumsq (row 64+c)
//     over nb contiguous floats, computes a = gamma*rstd, b = beta - mean*a.
// ---------------------------------------------------------------------------
__global__ __launch_bounds__(256) void stats_kernel(
    const float* __restrict__ partialsT, int nb,
    const float* __restrict__ gamma, const float* __restrict__ beta,
    float* __restrict__ ab, int n_out)
{
    const int t    = threadIdx.x;
    const int lane = t & 63;
    const int wave = t >> 6;
    const int c    = blockIdx.x;

    float sA = 0.f, sB = 0.f;
    for (int b = t; b < nb; b += 256) {
        sA += partialsT[(size_t)c * NB_PAD + b];
        sB += partialsT[(size_t)(C_OUTC + c) * NB_PAD + b];
    }
    #pragma unroll
    for (int off = 1; off < 64; off <<= 1) {
        sA += __shfl_xor(sA, off, 64);
        sB += __shfl_xor(sB, off, 64);
    }
    __shared__ float red[8];
    if (lane == 0) { red[wave] = sA; red[4 + wave] = sB; }
    __syncthreads();
    if (t == 0) {
        const float S1 = (red[0] + red[1]) + (red[2] + red[3]);
        const float S2 = (red[4] + red[5]) + (red[6] + red[7]);
        const float invN = 1.0f / (float)n_out;
        const float mean = S1 * invN;
        const float var  = S2 * invN - mean * mean;
        const float rstd = rsqrtf(var + BN_EPS);
        const float a    = gamma[c] * rstd;
        ab[c]          = a;
        ab[C_OUTC + c] = beta[c] - mean * a;
    }
}

// ---------------------------------------------------------------------------
// K3: in-place affine normalize: y = raw*a[c] + b[c], float4.
// ---------------------------------------------------------------------------
__global__ __launch_bounds__(256) void bn_kernel(
    float* __restrict__ out, const float* __restrict__ ab, long n4)
{
    const long i = (long)blockIdx.x * blockDim.x + threadIdx.x;
    if (i >= n4) return;
    const int c4 = (int)(i & 15); // 64 channels / 4 per float4
    float4 v = reinterpret_cast<float4*>(out)[i];
    const float4 a  = reinterpret_cast<const float4*>(ab)[c4];
    const float4 bb = reinterpret_cast<const float4*>(ab + C_OUTC)[c4];
    v.x = v.x * a.x + bb.x;
    v.y = v.y * a.y + bb.y;
    v.z = v.z * a.z + bb.z;
    v.w = v.w * a.w + bb.w;
    reinterpret_cast<float4*>(out)[i] = v;
}

// ---------------------------------------------------------------------------
extern "C" void kernel_launch(void* const* d_in, const int* in_sizes, int n_in,
                              void* d_out, int out_size, void* d_ws, size_t ws_size,
                              hipStream_t stream) {
    const float* data   = (const float*)d_in[0];
    const float* weight = (const float*)d_in[1];
    const float* bias   = (const float*)d_in[2];
    const float* gamma  = (const float*)d_in[3];
    const float* beta   = (const float*)d_in[4];
    const int*   neigh  = (const int*)d_in[5];

    const int n_out = in_sizes[5] / KNBR; // 250000
    float* out = (float*)d_out;

    const int nb = (n_out + 255) / 256;   // 977 blocks

    // Workspace: partialsT [128*NB_PAD] floats, then ab [128] floats.
    float* partialsT = (float*)d_ws;
    float* ab = partialsT + (size_t)128 * NB_PAD;

    hipLaunchKernelGGL(conv_kernel, dim3(nb), dim3(256), 0, stream,
                       data, weight, bias, neigh, out, partialsT, n_out);
    hipLaunchKernelGGL(stats_kernel, dim3(C_OUTC), dim3(256), 0, stream,
                       partialsT, nb, gamma, beta, ab, n_out);
    const long n4 = (long)n_out * C_OUTC / 4; // 4,000,000
    hipLaunchKernelGGL(bn_kernel, dim3((unsigned)((n4 + 255) / 256)), dim3(256), 0, stream,
                       out, ab, n4);
}